// Round 1
// baseline (286.484 us; speedup 1.0000x reference)
//
#include <hip/hip_runtime.h>

// MultiHeadContrastive on MI355X (gfx950).
// Pipeline: zero -> convert/transpose weights to bf16 -> label meta (hist/nfg)
//   -> GEMM1 (X@W1+b, relu, bf16 H) -> GEMM2 (+bias, L2-normalize, bf16 Z)
//   -> class sums S_c -> fused NxN sim reductions (denom/numer/sum-exp per row)
//   -> per-row losses + weighted reduction -> write 2 floats.
// Workspace required: ~12.8 MB.

typedef __attribute__((ext_vector_type(8))) short bs8;   // 8 x bf16 (4 VGPRs)
typedef __attribute__((ext_vector_type(4))) float f4;    // MFMA accumulator

#define MFMA_BF16(a, b, c) __builtin_amdgcn_mfma_f32_16x16x32_bf16((a), (b), (c), 0, 0, 0)

__device__ __forceinline__ unsigned short f2bf(float f) {
  unsigned int u = __float_as_uint(f);
  u = (u + 0x7fffu + ((u >> 16) & 1u)) >> 16;   // RNE
  return (unsigned short)u;
}
__device__ __forceinline__ float bf2f(unsigned short s) {
  return __uint_as_float(((unsigned int)s) << 16);
}

// ---------------- workspace layout (bytes) ----------------
constexpr size_t O_W1T  = 0;          // 512x1024 bf16 (rows 0..255 fg, 256..511 cls), W1T[n][k]
constexpr size_t O_W2TF = 1048576;    // 64x256 bf16, W2Tf[d][h]
constexpr size_t O_W2TC = 1081344;    // 128x256 bf16
constexpr size_t O_H    = 1146880;    // 8192x512 bf16 (cols 0..255 fg-h, 256..511 cls-h)
constexpr size_t O_ZF   = 9535488;    // 8192x64 bf16 normalized
constexpr size_t O_ZC   = 10584064;   // 8192x128 bf16 normalized
constexpr size_t O_SCLS = 12681216;   // 32x128 f32 class sums      [zeroed]
constexpr size_t O_ROWD = 12697600;   // 8192 f32 denom (fg head)   [zeroed]
constexpr size_t O_ROWN = 12730368;   // 8192 f32 numer (fg head)   [zeroed]
constexpr size_t O_ROWS = 12763136;   // 8192 f32 sum-exp (cls)     [zeroed]
constexpr size_t O_SCAL = 12795904;   // 4 f32: w_fg, wl_fg, w_c, wl_c [zeroed]
constexpr size_t O_HIST = 12795920;   // 32 int                     [zeroed]
constexpr size_t O_NFG  = 12796048;   // 1 int                      [zeroed]
constexpr int ZERO_WORDS = (int)((O_NFG + 4 - O_SCLS) / 4);  // 28709

// ---------------- tiny kernels ----------------
__global__ void __launch_bounds__(256) zero_kernel(float* __restrict__ p, int n) {
  int i = blockIdx.x * 256 + threadIdx.x;
  if (i < n) p[i] = 0.f;
}

__global__ void __launch_bounds__(256) convertw_kernel(
    const float* __restrict__ fgw1, const float* __restrict__ clsw1,
    const float* __restrict__ fgw2, const float* __restrict__ clsw2,
    unsigned short* __restrict__ W1T, unsigned short* __restrict__ W2Tf,
    unsigned short* __restrict__ W2Tc) {
  int i = blockIdx.x * 256 + threadIdx.x;    // grid covers exactly 573440
  if (i < 512 * 1024) {
    int n = i >> 10, k = i & 1023;
    float v = (n < 256) ? fgw1[k * 256 + n] : clsw1[k * 256 + (n - 256)];
    W1T[i] = f2bf(v);
  } else {
    int j = i - 512 * 1024;
    if (j < 64 * 256) {
      int d = j >> 8, h = j & 255;
      W2Tf[j] = f2bf(fgw2[h * 64 + d]);
    } else {
      j -= 64 * 256;
      int d = j >> 8, h = j & 255;
      W2Tc[j] = f2bf(clsw2[h * 128 + d]);
    }
  }
}

__global__ void __launch_bounds__(256) meta_kernel(const int* __restrict__ labels,
                                                   int* __restrict__ hist,
                                                   int* __restrict__ nfg) {
  __shared__ int sh[33];
  const int t = threadIdx.x;
  if (t < 33) sh[t] = 0;
  __syncthreads();
  int lab = labels[blockIdx.x * 256 + t];
  if (lab >= 0 && lab < 32) atomicAdd(&sh[lab], 1);  // ~ignore (label != -1)
  if (lab > 0) atomicAdd(&sh[32], 1);                // fg count
  __syncthreads();
  if (t < 32 && sh[t] > 0) atomicAdd(&hist[t], sh[t]);
  if (t == 32 && sh[32] > 0) atomicAdd(nfg, sh[32]);
}

// ---------------- GEMM1: H = relu(X @ W1 + b1), both heads ----------------
// grid (64, 8): 128-row x 64-col tiles, K=1024 in steps of 32.
__global__ void __launch_bounds__(256) gemm1_kernel(
    const float* __restrict__ X, const unsigned short* __restrict__ W1T,
    const float* __restrict__ b1f, const float* __restrict__ b1c,
    unsigned short* __restrict__ H) {
  __shared__ __align__(16) unsigned short lA[128 * 40];  // pad 32->40 for banks
  __shared__ __align__(16) unsigned short lB[64 * 40];
  const int t = threadIdx.x;
  const int w = t >> 6, lane = t & 63, ln = lane & 15, quad = lane >> 4;
  const int m0 = blockIdx.x * 128, n0 = blockIdx.y * 64;

  f4 acc[2][4];
#pragma unroll
  for (int rs = 0; rs < 2; rs++)
#pragma unroll
    for (int s = 0; s < 4; s++) acc[rs][s] = (f4){0.f, 0.f, 0.f, 0.f};

  for (int k0 = 0; k0 < 1024; k0 += 32) {
    __syncthreads();
#pragma unroll
    for (int i = 0; i < 2; i++) {
      int ch = t + i * 256;            // 512 chunks of 8 elems: 128 rows x 32 k
      int r = ch >> 2, c = (ch & 3) * 8;
      const float* xp = X + (size_t)(m0 + r) * 1024 + k0 + c;
      float4 x0 = *(const float4*)xp;
      float4 x1 = *(const float4*)(xp + 4);
      bs8 av;
      av[0] = (short)f2bf(x0.x); av[1] = (short)f2bf(x0.y);
      av[2] = (short)f2bf(x0.z); av[3] = (short)f2bf(x0.w);
      av[4] = (short)f2bf(x1.x); av[5] = (short)f2bf(x1.y);
      av[6] = (short)f2bf(x1.z); av[7] = (short)f2bf(x1.w);
      *(bs8*)&lA[r * 40 + c] = av;
    }
    {
      int r = t >> 2, c = (t & 3) * 8;  // 64 rows x 32 k
      *(bs8*)&lB[r * 40 + c] = *(const bs8*)(W1T + (size_t)(n0 + r) * 1024 + k0 + c);
    }
    __syncthreads();
    bs8 af0 = *(const bs8*)&lA[(w * 32 + ln) * 40 + quad * 8];
    bs8 af1 = *(const bs8*)&lA[(w * 32 + 16 + ln) * 40 + quad * 8];
#pragma unroll
    for (int s = 0; s < 4; s++) {
      bs8 bf = *(const bs8*)&lB[(s * 16 + ln) * 40 + quad * 8];
      acc[0][s] = MFMA_BF16(af0, bf, acc[0][s]);
      acc[1][s] = MFMA_BF16(af1, bf, acc[1][s]);
    }
  }
#pragma unroll
  for (int s = 0; s < 4; s++) {
    int n = n0 + s * 16 + ln;
    float b = (n < 256) ? b1f[n] : b1c[n - 256];
#pragma unroll
    for (int rs = 0; rs < 2; rs++)
#pragma unroll
      for (int r = 0; r < 4; r++) {
        float v = fmaxf(acc[rs][s][r] + b, 0.f);
        H[(size_t)(m0 + w * 32 + rs * 16 + quad * 4 + r) * 512 + n] = f2bf(v);
      }
  }
}

// ---------------- GEMM2: Z = normalize(H @ W2 + b2), both heads ----------------
// grid (128): 64 rows/block, wave handles 16 rows.
__global__ void __launch_bounds__(256) gemm2_kernel(
    const unsigned short* __restrict__ H,
    const unsigned short* __restrict__ W2Tf, const unsigned short* __restrict__ W2Tc,
    const float* __restrict__ b2f, const float* __restrict__ b2c,
    unsigned short* __restrict__ Zf, unsigned short* __restrict__ Zc) {
  const int t = threadIdx.x;
  const int w = t >> 6, lane = t & 63, ln = lane & 15, quad = lane >> 4;
  const int rw = blockIdx.x * 64 + w * 16;
  const unsigned short* hrow = H + (size_t)(rw + ln) * 512;

  {  // fg head: K=256 (H cols 0..255), N=64
    f4 acc[4];
#pragma unroll
    for (int s = 0; s < 4; s++) acc[s] = (f4){0.f, 0.f, 0.f, 0.f};
#pragma unroll
    for (int ks = 0; ks < 8; ks++) {
      bs8 af = *(const bs8*)(hrow + ks * 32 + quad * 8);
#pragma unroll
      for (int s = 0; s < 4; s++) {
        bs8 bf = *(const bs8*)(W2Tf + (size_t)(s * 16 + ln) * 256 + ks * 32 + quad * 8);
        acc[s] = MFMA_BF16(af, bf, acc[s]);
      }
    }
    float ss[4] = {0.f, 0.f, 0.f, 0.f};
#pragma unroll
    for (int s = 0; s < 4; s++) {
      float b = b2f[s * 16 + ln];
#pragma unroll
      for (int r = 0; r < 4; r++) {
        acc[s][r] += b;
        ss[r] = fmaf(acc[s][r], acc[s][r], ss[r]);
      }
    }
#pragma unroll
    for (int r = 0; r < 4; r++) {
#pragma unroll
      for (int off = 1; off < 16; off <<= 1) ss[r] += __shfl_xor(ss[r], off, 64);
      float sc = 1.f / fmaxf(sqrtf(ss[r]), 1e-8f);
#pragma unroll
      for (int s = 0; s < 4; s++)
        Zf[(size_t)(rw + quad * 4 + r) * 64 + s * 16 + ln] = f2bf(acc[s][r] * sc);
    }
  }
  {  // cls head: K=256 (H cols 256..511), N=128
    f4 acc[8];
#pragma unroll
    for (int s = 0; s < 8; s++) acc[s] = (f4){0.f, 0.f, 0.f, 0.f};
#pragma unroll
    for (int ks = 0; ks < 8; ks++) {
      bs8 af = *(const bs8*)(hrow + 256 + ks * 32 + quad * 8);
#pragma unroll
      for (int s = 0; s < 8; s++) {
        bs8 bf = *(const bs8*)(W2Tc + (size_t)(s * 16 + ln) * 256 + ks * 32 + quad * 8);
        acc[s] = MFMA_BF16(af, bf, acc[s]);
      }
    }
    float ss[4] = {0.f, 0.f, 0.f, 0.f};
#pragma unroll
    for (int s = 0; s < 8; s++) {
      float b = b2c[s * 16 + ln];
#pragma unroll
      for (int r = 0; r < 4; r++) {
        acc[s][r] += b;
        ss[r] = fmaf(acc[s][r], acc[s][r], ss[r]);
      }
    }
#pragma unroll
    for (int r = 0; r < 4; r++) {
#pragma unroll
      for (int off = 1; off < 16; off <<= 1) ss[r] += __shfl_xor(ss[r], off, 64);
      float sc = 1.f / fmaxf(sqrtf(ss[r]), 1e-8f);
#pragma unroll
      for (int s = 0; s < 8; s++)
        Zc[(size_t)(rw + quad * 4 + r) * 128 + s * 16 + ln] = f2bf(acc[s][r] * sc);
    }
  }
}

// ---------------- class sums S_c = sum_{label_j==c} z_cls_j ----------------
__global__ void __launch_bounds__(128) scls_kernel(const unsigned short* __restrict__ Zc,
                                                   const int* __restrict__ labels,
                                                   float* __restrict__ Scls) {
  const int c = blockIdx.x + 1;     // classes 1..20
  const int t = threadIdx.x;
  const int r0 = blockIdx.y * 1024;
  float acc = 0.f;
#pragma unroll 4
  for (int r = r0; r < r0 + 1024; r++) {
    if (labels[r] == c) acc += bf2f(Zc[(size_t)r * 128 + t]);
  }
  atomicAdd(&Scls[c * 128 + t], acc);
}

// ---------------- fused NxN sim reductions ----------------
// grid (64, 8): 128 rows/block x 1024-col chunk; per row accumulate
//   rowD = sum_{j!=i} exp(sim_fg), rowN = sum over fg cols, rowS = sum exp(sim_cls)
__global__ void __launch_bounds__(256) sim_kernel(
    const unsigned short* __restrict__ Zf, const unsigned short* __restrict__ Zc,
    const int* __restrict__ labels,
    float* __restrict__ rowD, float* __restrict__ rowN, float* __restrict__ rowS) {
  __shared__ __align__(16) unsigned short sZf[64 * 72];   // 64 cols x 64 k (pad 72)
  __shared__ __align__(16) unsigned short sZc[64 * 136];  // 64 cols x 128 k (pad 136)
  __shared__ float sFg[64];
  const int t = threadIdx.x;
  const int w = t >> 6, lane = t & 63, ln = lane & 15, quad = lane >> 4;
  const int m0 = blockIdx.x * 128;
  const int rbase = m0 + w * 32;

  // row fragments (loop-invariant)
  bs8 afg[2][2], acl[2][4];
#pragma unroll
  for (int rs = 0; rs < 2; rs++) {
    const unsigned short* zf = Zf + (size_t)(rbase + rs * 16 + ln) * 64;
    const unsigned short* zc = Zc + (size_t)(rbase + rs * 16 + ln) * 128;
#pragma unroll
    for (int s = 0; s < 2; s++) afg[rs][s] = *(const bs8*)(zf + s * 32 + quad * 8);
#pragma unroll
    for (int s = 0; s < 4; s++) acl[rs][s] = *(const bs8*)(zc + s * 32 + quad * 8);
  }

  float dacc[2][4] = {}, nacc[2][4] = {}, sacc[2][4] = {};

  for (int ct = 0; ct < 16; ct++) {
    const int c0 = blockIdx.y * 1024 + ct * 64;
    __syncthreads();
#pragma unroll
    for (int i = 0; i < 2; i++) {
      int ch = t + i * 256;
      int j = ch >> 3, c8 = (ch & 7) * 8;
      *(bs8*)&sZf[j * 72 + c8] = *(const bs8*)(Zf + (size_t)(c0 + j) * 64 + c8);
    }
#pragma unroll
    for (int i = 0; i < 4; i++) {
      int ch = t + i * 256;
      int j = ch >> 4, c8 = (ch & 15) * 8;
      *(bs8*)&sZc[j * 136 + c8] = *(const bs8*)(Zc + (size_t)(c0 + j) * 128 + c8);
    }
    if (t < 64) sFg[t] = (labels[c0 + t] > 0) ? 1.f : 0.f;
    __syncthreads();

#pragma unroll
    for (int s = 0; s < 4; s++) {
      const int lcol = s * 16 + ln;
      const int colg = c0 + lcol;
      const float fgc = sFg[lcol];
      // fg head (K=64)
      bs8 b0 = *(const bs8*)&sZf[lcol * 72 + quad * 8];
      bs8 b1 = *(const bs8*)&sZf[lcol * 72 + 32 + quad * 8];
#pragma unroll
      for (int rs = 0; rs < 2; rs++) {
        f4 c = {0.f, 0.f, 0.f, 0.f};
        c = MFMA_BF16(afg[rs][0], b0, c);
        c = MFMA_BF16(afg[rs][1], b1, c);
        const int rq = rbase + rs * 16 + quad * 4;
#pragma unroll
        for (int r = 0; r < 4; r++) {
          float e = __expf(c[r] * 5.0f);
          if (rq + r == colg) e = 0.f;   // exclude diagonal
          dacc[rs][r] += e;
          nacc[rs][r] = fmaf(fgc, e, nacc[rs][r]);
        }
      }
      // cls head (K=128)
      bs8 bc0 = *(const bs8*)&sZc[lcol * 136 + quad * 8];
      bs8 bc1 = *(const bs8*)&sZc[lcol * 136 + 32 + quad * 8];
      bs8 bc2 = *(const bs8*)&sZc[lcol * 136 + 64 + quad * 8];
      bs8 bc3 = *(const bs8*)&sZc[lcol * 136 + 96 + quad * 8];
#pragma unroll
      for (int rs = 0; rs < 2; rs++) {
        f4 c = {0.f, 0.f, 0.f, 0.f};
        c = MFMA_BF16(acl[rs][0], bc0, c);
        c = MFMA_BF16(acl[rs][1], bc1, c);
        c = MFMA_BF16(acl[rs][2], bc2, c);
        c = MFMA_BF16(acl[rs][3], bc3, c);
        const int rq = rbase + rs * 16 + quad * 4;
#pragma unroll
        for (int r = 0; r < 4; r++) {
          float e = __expf(c[r] * 5.0f);
          if (rq + r == colg) e = 0.f;
          sacc[rs][r] += e;
        }
      }
    }
  }

#pragma unroll
  for (int rs = 0; rs < 2; rs++)
#pragma unroll
    for (int r = 0; r < 4; r++) {
      float d = dacc[rs][r], n = nacc[rs][r], s = sacc[rs][r];
#pragma unroll
      for (int off = 1; off < 16; off <<= 1) {
        d += __shfl_xor(d, off, 64);
        n += __shfl_xor(n, off, 64);
        s += __shfl_xor(s, off, 64);
      }
      if (ln == 0) {
        int row = rbase + rs * 16 + quad * 4 + r;
        atomicAdd(&rowD[row], d);
        atomicAdd(&rowN[row], n);
        atomicAdd(&rowS[row], s);
      }
    }
}

// ---------------- per-row losses + weighted reduction ----------------
__global__ void __launch_bounds__(256) finalize_kernel(
    const unsigned short* __restrict__ Zc,
    const int* __restrict__ labels, const float* __restrict__ ious,
    const float* __restrict__ rowD, const float* __restrict__ rowN,
    const float* __restrict__ rowS, const float* __restrict__ Scls,
    const int* __restrict__ hist, const int* __restrict__ nfg,
    float* __restrict__ scal) {
  __shared__ float red[4][4];
  const int t = threadIdx.x, w = t >> 6, lane = t & 63;
  float aw0 = 0.f, al0 = 0.f, aw1 = 0.f, al1 = 0.f;
  const int NFG = *nfg;
  for (int it = 0; it < 16; it++) {
    const int i = it * 512 + blockIdx.x * 4 + w;   // wave-uniform row
    const int lab = labels[i];
    if (lab > 0 && lab < 32) {                     // fg row
      const float iou = ious[i];
      const float iw = (iou > 0.5f) ? iou : 0.f;
      float dot = 0.f, ssq = 0.f;
#pragma unroll
      for (int p = 0; p < 2; p++) {
        const int k = lane + p * 64;
        const float z = bf2f(Zc[(size_t)i * 128 + k]);
        dot = fmaf(z, Scls[lab * 128 + k], dot);
        ssq = fmaf(z, z, ssq);
      }
#pragma unroll
      for (int off = 1; off < 64; off <<= 1) {
        dot += __shfl_xor(dot, off, 64);
        ssq += __shfl_xor(ssq, off, 64);
      }
      if (lane == 0) {
        if (NFG - 1 > 0) {  // n_pos = NFG - 1 for fg rows
          const float loss = logf(rowD[i] + 2e-8f) - logf(rowN[i] + 1e-8f);
          aw0 += iw;
          al0 += iw * loss;
        }
        const int npc = hist[lab];
        if (npc > 0) {
          const float logden = logf(rowS[i]);
          // sum_log_p = sum_{pos,j!=i}(sim) - (npc-1)*logden + NEG(diag)
          const float slp = (dot - ssq) * 5.0f - (float)(npc - 1) * logden - 1e9f;
          aw1 += iw;
          al1 += iw * (-slp / ((float)npc + 1e-8f));
        }
      }
    }
  }
  if (lane == 0) { red[w][0] = aw0; red[w][1] = al0; red[w][2] = aw1; red[w][3] = al1; }
  __syncthreads();
  if (t < 4) atomicAdd(&scal[t], red[0][t] + red[1][t] + red[2][t] + red[3][t]);
}

__global__ void writeout_kernel(const float* __restrict__ scal, float* __restrict__ out) {
  if (threadIdx.x == 0) {
    out[0] = scal[1] / (scal[0] + 1e-8f);
    out[1] = scal[3] / (scal[2] + 1e-8f);
  }
}

// ---------------- launch ----------------
extern "C" void kernel_launch(void* const* d_in, const int* in_sizes, int n_in,
                              void* d_out, int out_size, void* d_ws, size_t ws_size,
                              hipStream_t stream) {
  (void)in_sizes; (void)n_in; (void)out_size; (void)ws_size;
  const float* roi   = (const float*)d_in[0];
  const int*   labels = (const int*)d_in[1];
  const float* ious  = (const float*)d_in[2];
  const float* fgw1  = (const float*)d_in[3];
  const float* fgb1  = (const float*)d_in[4];
  const float* fgw2  = (const float*)d_in[5];
  const float* fgb2  = (const float*)d_in[6];
  const float* clsw1 = (const float*)d_in[7];
  const float* clsb1 = (const float*)d_in[8];
  const float* clsw2 = (const float*)d_in[9];
  const float* clsb2 = (const float*)d_in[10];

  char* ws = (char*)d_ws;
  unsigned short* W1T  = (unsigned short*)(ws + O_W1T);
  unsigned short* W2Tf = (unsigned short*)(ws + O_W2TF);
  unsigned short* W2Tc = (unsigned short*)(ws + O_W2TC);
  unsigned short* Hb   = (unsigned short*)(ws + O_H);
  unsigned short* Zf   = (unsigned short*)(ws + O_ZF);
  unsigned short* Zc   = (unsigned short*)(ws + O_ZC);
  float* Scls = (float*)(ws + O_SCLS);
  float* rowD = (float*)(ws + O_ROWD);
  float* rowN = (float*)(ws + O_ROWN);
  float* rowS = (float*)(ws + O_ROWS);
  float* scal = (float*)(ws + O_SCAL);
  int* hist = (int*)(ws + O_HIST);
  int* nfg  = (int*)(ws + O_NFG);
  float* out = (float*)d_out;

  hipLaunchKernelGGL(zero_kernel, dim3((ZERO_WORDS + 255) / 256), dim3(256), 0, stream,
                     (float*)(ws + O_SCLS), ZERO_WORDS);
  hipLaunchKernelGGL(convertw_kernel, dim3(2240), dim3(256), 0, stream,
                     fgw1, clsw1, fgw2, clsw2, W1T, W2Tf, W2Tc);
  hipLaunchKernelGGL(meta_kernel, dim3(32), dim3(256), 0, stream, labels, hist, nfg);
  hipLaunchKernelGGL(gemm1_kernel, dim3(64, 8), dim3(256), 0, stream,
                     roi, W1T, fgb1, clsb1, Hb);
  hipLaunchKernelGGL(gemm2_kernel, dim3(128), dim3(256), 0, stream,
                     Hb, W2Tf, W2Tc, fgb2, clsb2, Zf, Zc);
  hipLaunchKernelGGL(scls_kernel, dim3(20, 8), dim3(128), 0, stream, Zc, labels, Scls);
  hipLaunchKernelGGL(sim_kernel, dim3(64, 8), dim3(256), 0, stream,
                     Zf, Zc, labels, rowD, rowN, rowS);
  hipLaunchKernelGGL(finalize_kernel, dim3(128), dim3(256), 0, stream,
                     Zc, labels, ious, rowD, rowN, rowS, Scls, hist, nfg, scal);
  hipLaunchKernelGGL(writeout_kernel, dim3(1), dim3(64), 0, stream, scal, out);
}

// Round 2
// 220.051 us; speedup vs baseline: 1.3019x; 1.3019x over previous
//
#include <hip/hip_runtime.h>

// MultiHeadContrastive on MI355X (gfx950).
// zero -> LDS-tiled transpose/convert weights -> meta (hist/nfg)
//   -> GEMM1 (X@W1+b, relu, bf16 H) -> GEMM2 (+bias, L2-normalize, bf16 Z)
//   -> class sums S_c -> fused NxN sim reductions (no diag check; corrected later)
//   -> per-row losses (diag corrections) + weighted reduction -> 2 floats.

typedef __attribute__((ext_vector_type(8))) short bs8;   // 8 x bf16 (4 VGPRs)
typedef __attribute__((ext_vector_type(4))) float f4;    // MFMA accumulator

#define MFMA_BF16(a, b, c) __builtin_amdgcn_mfma_f32_16x16x32_bf16((a), (b), (c), 0, 0, 0)

#if defined(__has_builtin)
#if __has_builtin(__builtin_amdgcn_exp2f)
#define EXP2F(x) __builtin_amdgcn_exp2f(x)
#endif
#endif
#ifndef EXP2F
#define EXP2F(x) exp2f(x)
#endif

#define K_LOG2E 7.2134752044448170f   // 5 * log2(e), for exp(sim/tau) = 2^(c*K)

__device__ __forceinline__ unsigned short f2bf(float f) {
  unsigned int u = __float_as_uint(f);
  u = (u + 0x7fffu + ((u >> 16) & 1u)) >> 16;   // RNE
  return (unsigned short)u;
}
__device__ __forceinline__ float bf2f(unsigned short s) {
  return __uint_as_float(((unsigned int)s) << 16);
}

// ---------------- workspace layout (bytes) ----------------
constexpr size_t O_W1T  = 0;          // 512x1024 bf16 (rows 0..255 fg, 256..511 cls), W1T[n][k]
constexpr size_t O_W2TF = 1048576;    // 64x256 bf16, W2Tf[d][h]
constexpr size_t O_W2TC = 1081344;    // 128x256 bf16
constexpr size_t O_H    = 1146880;    // 8192x512 bf16 (cols 0..255 fg-h, 256..511 cls-h)
constexpr size_t O_ZF   = 9535488;    // 8192x64 bf16 normalized
constexpr size_t O_ZC   = 10584064;   // 8192x128 bf16 normalized
constexpr size_t O_SCLS = 12681216;   // 32x128 f32 class sums      [zeroed]
constexpr size_t O_ROWD = 12697600;   // 8192 f32 denom (fg head)   [zeroed]
constexpr size_t O_ROWN = 12730368;   // 8192 f32 numer (fg head)   [zeroed]
constexpr size_t O_ROWS = 12763136;   // 8192 f32 sum-exp (cls)     [zeroed]
constexpr size_t O_SCAL = 12795904;   // 4 f32: w_fg, wl_fg, w_c, wl_c [zeroed]
constexpr size_t O_HIST = 12795920;   // 32 int                     [zeroed]
constexpr size_t O_NFG  = 12796048;   // 1 int                      [zeroed]
constexpr int ZERO_WORDS = (int)((O_NFG + 4 - O_SCLS) / 4);  // 28709

// ---------------- tiny kernels ----------------
__global__ void __launch_bounds__(256) zero_kernel(float* __restrict__ p, int n) {
  int i = blockIdx.x * 256 + threadIdx.x;
  if (i < n) p[i] = 0.f;
}

// LDS-tiled transpose + f32->bf16: dst[c][r] = src[r][c]. grid (64, 4).
__global__ void __launch_bounds__(256) transp_kernel(
    const float* __restrict__ fgw1, const float* __restrict__ clsw1,
    const float* __restrict__ fgw2, const float* __restrict__ clsw2,
    unsigned short* __restrict__ W1T, unsigned short* __restrict__ W2Tf,
    unsigned short* __restrict__ W2Tc) {
  __shared__ float tile[64][65];
  const int m = blockIdx.y;
  const float* src;
  unsigned short* dst;
  int R, C;
  if (m == 0)      { src = fgw1;  dst = W1T;              R = 1024; C = 256; }
  else if (m == 1) { src = clsw1; dst = W1T + 256 * 1024; R = 1024; C = 256; }
  else if (m == 2) { src = fgw2;  dst = W2Tf;             R = 256;  C = 64;  }
  else             { src = clsw2; dst = W2Tc;             R = 256;  C = 128; }
  const int cT = C >> 6;
  if (blockIdx.x >= (R >> 6) * cT) return;
  const int r0 = (blockIdx.x / cT) << 6, c0 = (blockIdx.x % cT) << 6;
  const int t = threadIdx.x;
  {
    const int rr = t >> 4, cc = (t & 15) << 2;
#pragma unroll
    for (int i = 0; i < 4; i++) {
      float4 v = *(const float4*)(src + (size_t)(r0 + rr + i * 16) * C + c0 + cc);
      tile[rr + i * 16][cc] = v.x; tile[rr + i * 16][cc + 1] = v.y;
      tile[rr + i * 16][cc + 2] = v.z; tile[rr + i * 16][cc + 3] = v.w;
    }
  }
  __syncthreads();
  {
    const int dr = t >> 2, dc = (t & 3) << 4;   // dst row (c-dim), dst col chunk (r-dim)
    bs8 o0, o1;
#pragma unroll
    for (int j = 0; j < 8; j++) o0[j] = (short)f2bf(tile[dc + j][dr]);
#pragma unroll
    for (int j = 0; j < 8; j++) o1[j] = (short)f2bf(tile[dc + 8 + j][dr]);
    unsigned short* dp = dst + (size_t)(c0 + dr) * R + r0 + dc;
    *(bs8*)dp = o0;
    *(bs8*)(dp + 8) = o1;
  }
}

__global__ void __launch_bounds__(256) meta_kernel(const int* __restrict__ labels,
                                                   int* __restrict__ hist,
                                                   int* __restrict__ nfg) {
  __shared__ int sh[33];
  const int t = threadIdx.x;
  if (t < 33) sh[t] = 0;
  __syncthreads();
  int lab = labels[blockIdx.x * 256 + t];
  if (lab >= 0 && lab < 32) atomicAdd(&sh[lab], 1);  // ~ignore (label != -1)
  if (lab > 0) atomicAdd(&sh[32], 1);                // fg count
  __syncthreads();
  if (t < 32 && sh[t] > 0) atomicAdd(&hist[t], sh[t]);
  if (t == 32 && sh[32] > 0) atomicAdd(nfg, sh[32]);
}

// ---------------- GEMM1: H = relu(X @ W1 + b1), both heads ----------------
// grid (64, 8): 128-row x 64-col tiles, K=1024 in steps of 32.
__global__ void __launch_bounds__(256) gemm1_kernel(
    const float* __restrict__ X, const unsigned short* __restrict__ W1T,
    const float* __restrict__ b1f, const float* __restrict__ b1c,
    unsigned short* __restrict__ H) {
  __shared__ __align__(16) unsigned short lA[128 * 40];
  __shared__ __align__(16) unsigned short lB[64 * 40];
  const int t = threadIdx.x;
  const int w = t >> 6, lane = t & 63, ln = lane & 15, quad = lane >> 4;
  const int m0 = blockIdx.x * 128, n0 = blockIdx.y * 64;

  f4 acc[2][4];
#pragma unroll
  for (int rs = 0; rs < 2; rs++)
#pragma unroll
    for (int s = 0; s < 4; s++) acc[rs][s] = (f4){0.f, 0.f, 0.f, 0.f};

  for (int k0 = 0; k0 < 1024; k0 += 32) {
    __syncthreads();
#pragma unroll
    for (int i = 0; i < 2; i++) {
      int ch = t + i * 256;
      int r = ch >> 2, c = (ch & 3) * 8;
      const float* xp = X + (size_t)(m0 + r) * 1024 + k0 + c;
      float4 x0 = *(const float4*)xp;
      float4 x1 = *(const float4*)(xp + 4);
      bs8 av;
      av[0] = (short)f2bf(x0.x); av[1] = (short)f2bf(x0.y);
      av[2] = (short)f2bf(x0.z); av[3] = (short)f2bf(x0.w);
      av[4] = (short)f2bf(x1.x); av[5] = (short)f2bf(x1.y);
      av[6] = (short)f2bf(x1.z); av[7] = (short)f2bf(x1.w);
      *(bs8*)&lA[r * 40 + c] = av;
    }
    {
      int r = t >> 2, c = (t & 3) * 8;
      *(bs8*)&lB[r * 40 + c] = *(const bs8*)(W1T + (size_t)(n0 + r) * 1024 + k0 + c);
    }
    __syncthreads();
    bs8 af0 = *(const bs8*)&lA[(w * 32 + ln) * 40 + quad * 8];
    bs8 af1 = *(const bs8*)&lA[(w * 32 + 16 + ln) * 40 + quad * 8];
#pragma unroll
    for (int s = 0; s < 4; s++) {
      bs8 bf = *(const bs8*)&lB[(s * 16 + ln) * 40 + quad * 8];
      acc[0][s] = MFMA_BF16(af0, bf, acc[0][s]);
      acc[1][s] = MFMA_BF16(af1, bf, acc[1][s]);
    }
  }
#pragma unroll
  for (int s = 0; s < 4; s++) {
    int n = n0 + s * 16 + ln;
    float b = (n < 256) ? b1f[n] : b1c[n - 256];
#pragma unroll
    for (int rs = 0; rs < 2; rs++)
#pragma unroll
      for (int r = 0; r < 4; r++) {
        float v = fmaxf(acc[rs][s][r] + b, 0.f);
        H[(size_t)(m0 + w * 32 + rs * 16 + quad * 4 + r) * 512 + n] = f2bf(v);
      }
  }
}

// ---------------- GEMM2: Z = normalize(H @ W2 + b2) ----------------
// grid (256): 32 rows/block; waves 0,1 = fg head; waves 2,3 = cls head.
__global__ void __launch_bounds__(256) gemm2_kernel(
    const unsigned short* __restrict__ H,
    const unsigned short* __restrict__ W2Tf, const unsigned short* __restrict__ W2Tc,
    const float* __restrict__ b2f, const float* __restrict__ b2c,
    unsigned short* __restrict__ Zf, unsigned short* __restrict__ Zc) {
  const int t = threadIdx.x;
  const int w = t >> 6, lane = t & 63, ln = lane & 15, quad = lane >> 4;
  const int rw = blockIdx.x * 32 + (w & 1) * 16;

  if (w < 2) {  // fg head: K=256 (H cols 0..255), N=64
    const unsigned short* hrow = H + (size_t)(rw + ln) * 512;
    f4 acc[4];
#pragma unroll
    for (int s = 0; s < 4; s++) acc[s] = (f4){0.f, 0.f, 0.f, 0.f};
#pragma unroll
    for (int ks = 0; ks < 8; ks++) {
      bs8 af = *(const bs8*)(hrow + ks * 32 + quad * 8);
#pragma unroll
      for (int s = 0; s < 4; s++) {
        bs8 bf = *(const bs8*)(W2Tf + (size_t)(s * 16 + ln) * 256 + ks * 32 + quad * 8);
        acc[s] = MFMA_BF16(af, bf, acc[s]);
      }
    }
    float ss[4] = {0.f, 0.f, 0.f, 0.f};
#pragma unroll
    for (int s = 0; s < 4; s++) {
      float b = b2f[s * 16 + ln];
#pragma unroll
      for (int r = 0; r < 4; r++) {
        acc[s][r] += b;
        ss[r] = fmaf(acc[s][r], acc[s][r], ss[r]);
      }
    }
#pragma unroll
    for (int r = 0; r < 4; r++) {
#pragma unroll
      for (int off = 1; off < 16; off <<= 1) ss[r] += __shfl_xor(ss[r], off, 64);
      float sc = 1.f / fmaxf(sqrtf(ss[r]), 1e-8f);
#pragma unroll
      for (int s = 0; s < 4; s++)
        Zf[(size_t)(rw + quad * 4 + r) * 64 + s * 16 + ln] = f2bf(acc[s][r] * sc);
    }
  } else {  // cls head: K=256 (H cols 256..511), N=128
    const unsigned short* hrow = H + (size_t)(rw + ln) * 512 + 256;
    f4 acc[8];
#pragma unroll
    for (int s = 0; s < 8; s++) acc[s] = (f4){0.f, 0.f, 0.f, 0.f};
#pragma unroll
    for (int ks = 0; ks < 8; ks++) {
      bs8 af = *(const bs8*)(hrow + ks * 32 + quad * 8);
#pragma unroll
      for (int s = 0; s < 8; s++) {
        bs8 bf = *(const bs8*)(W2Tc + (size_t)(s * 16 + ln) * 256 + ks * 32 + quad * 8);
        acc[s] = MFMA_BF16(af, bf, acc[s]);
      }
    }
    float ss[4] = {0.f, 0.f, 0.f, 0.f};
#pragma unroll
    for (int s = 0; s < 8; s++) {
      float b = b2c[s * 16 + ln];
#pragma unroll
      for (int r = 0; r < 4; r++) {
        acc[s][r] += b;
        ss[r] = fmaf(acc[s][r], acc[s][r], ss[r]);
      }
    }
#pragma unroll
    for (int r = 0; r < 4; r++) {
#pragma unroll
      for (int off = 1; off < 16; off <<= 1) ss[r] += __shfl_xor(ss[r], off, 64);
      float sc = 1.f / fmaxf(sqrtf(ss[r]), 1e-8f);
#pragma unroll
      for (int s = 0; s < 8; s++)
        Zc[(size_t)(rw + quad * 4 + r) * 128 + s * 16 + ln] = f2bf(acc[s][r] * sc);
    }
  }
}

// ---------------- class sums S_c = sum_{label_j==c} z_cls_j ----------------
__global__ void __launch_bounds__(128) scls_kernel(const unsigned short* __restrict__ Zc,
                                                   const int* __restrict__ labels,
                                                   float* __restrict__ Scls) {
  const int c = blockIdx.x + 1;     // classes 1..20
  const int t = threadIdx.x;
  const int r0 = blockIdx.y * 256;
  float acc = 0.f;
#pragma unroll 4
  for (int r = r0; r < r0 + 256; r++) {
    if (labels[r] == c) acc += bf2f(Zc[(size_t)r * 128 + t]);
  }
  atomicAdd(&Scls[c * 128 + t], acc);
}

// ---------------- fused NxN sim reductions ----------------
// grid (64, 16): 128 rows/block x 512-col chunk. Diagonal included here;
// corrected in finalize (exact same bf16 z -> tiny fp32 re-association error).
__global__ void __launch_bounds__(256) sim_kernel(
    const unsigned short* __restrict__ Zf, const unsigned short* __restrict__ Zc,
    const int* __restrict__ labels,
    float* __restrict__ rowD, float* __restrict__ rowN, float* __restrict__ rowS) {
  __shared__ __align__(16) unsigned short sZf[64 * 72];
  __shared__ __align__(16) unsigned short sZc[64 * 136];
  __shared__ float sFg[64];
  const int t = threadIdx.x;
  const int w = t >> 6, lane = t & 63, ln = lane & 15, quad = lane >> 4;
  const int rbase = blockIdx.x * 128 + w * 32;

  bs8 afg[2][2], acl[2][4];
#pragma unroll
  for (int rs = 0; rs < 2; rs++) {
    const unsigned short* zf = Zf + (size_t)(rbase + rs * 16 + ln) * 64;
    const unsigned short* zc = Zc + (size_t)(rbase + rs * 16 + ln) * 128;
#pragma unroll
    for (int s = 0; s < 2; s++) afg[rs][s] = *(const bs8*)(zf + s * 32 + quad * 8);
#pragma unroll
    for (int s = 0; s < 4; s++) acl[rs][s] = *(const bs8*)(zc + s * 32 + quad * 8);
  }

  float dacc[2][4] = {}, nacc[2][4] = {}, sacc[2][4] = {};

  for (int ct = 0; ct < 8; ct++) {
    const int c0 = blockIdx.y * 512 + ct * 64;
    __syncthreads();
#pragma unroll
    for (int i = 0; i < 2; i++) {
      int ch = t + i * 256;
      int j = ch >> 3, c8 = (ch & 7) * 8;
      *(bs8*)&sZf[j * 72 + c8] = *(const bs8*)(Zf + (size_t)(c0 + j) * 64 + c8);
    }
#pragma unroll
    for (int i = 0; i < 4; i++) {
      int ch = t + i * 256;
      int j = ch >> 4, c8 = (ch & 15) * 8;
      *(bs8*)&sZc[j * 136 + c8] = *(const bs8*)(Zc + (size_t)(c0 + j) * 128 + c8);
    }
    if (t < 64) sFg[t] = (labels[c0 + t] > 0) ? 1.f : 0.f;
    __syncthreads();

#pragma unroll
    for (int s = 0; s < 4; s++) {
      const int lcol = s * 16 + ln;
      const float fgc = sFg[lcol];
      // fg head (K=64)
      bs8 b0 = *(const bs8*)&sZf[lcol * 72 + quad * 8];
      bs8 b1 = *(const bs8*)&sZf[lcol * 72 + 32 + quad * 8];
#pragma unroll
      for (int rs = 0; rs < 2; rs++) {
        f4 c = {0.f, 0.f, 0.f, 0.f};
        c = MFMA_BF16(afg[rs][0], b0, c);
        c = MFMA_BF16(afg[rs][1], b1, c);
#pragma unroll
        for (int r = 0; r < 4; r++) {
          float e = EXP2F(c[r] * K_LOG2E);
          dacc[rs][r] += e;
          nacc[rs][r] = fmaf(fgc, e, nacc[rs][r]);
        }
      }
      // cls head (K=128)
      bs8 bc0 = *(const bs8*)&sZc[lcol * 136 + quad * 8];
      bs8 bc1 = *(const bs8*)&sZc[lcol * 136 + 32 + quad * 8];
      bs8 bc2 = *(const bs8*)&sZc[lcol * 136 + 64 + quad * 8];
      bs8 bc3 = *(const bs8*)&sZc[lcol * 136 + 96 + quad * 8];
#pragma unroll
      for (int rs = 0; rs < 2; rs++) {
        f4 c = {0.f, 0.f, 0.f, 0.f};
        c = MFMA_BF16(acl[rs][0], bc0, c);
        c = MFMA_BF16(acl[rs][1], bc1, c);
        c = MFMA_BF16(acl[rs][2], bc2, c);
        c = MFMA_BF16(acl[rs][3], bc3, c);
#pragma unroll
        for (int r = 0; r < 4; r++) sacc[rs][r] += EXP2F(c[r] * K_LOG2E);
      }
    }
  }

#pragma unroll
  for (int rs = 0; rs < 2; rs++)
#pragma unroll
    for (int r = 0; r < 4; r++) {
      float d = dacc[rs][r], n = nacc[rs][r], s = sacc[rs][r];
#pragma unroll
      for (int off = 1; off < 16; off <<= 1) {
        d += __shfl_xor(d, off, 64);
        n += __shfl_xor(n, off, 64);
        s += __shfl_xor(s, off, 64);
      }
      if (ln == 0) {
        int row = rbase + rs * 16 + quad * 4 + r;
        atomicAdd(&rowD[row], d);
        atomicAdd(&rowN[row], n);
        atomicAdd(&rowS[row], s);
      }
    }
}

// ---------------- per-row losses (with diag corrections) + reduction ----------------
__global__ void __launch_bounds__(256) finalize_kernel(
    const unsigned short* __restrict__ Zf, const unsigned short* __restrict__ Zc,
    const int* __restrict__ labels, const float* __restrict__ ious,
    const float* __restrict__ rowD, const float* __restrict__ rowN,
    const float* __restrict__ rowS, const float* __restrict__ Scls,
    const int* __restrict__ hist, const int* __restrict__ nfg,
    float* __restrict__ scal) {
  __shared__ float red[4][4];
  const int t = threadIdx.x, w = t >> 6, lane = t & 63;
  float aw0 = 0.f, al0 = 0.f, aw1 = 0.f, al1 = 0.f;
  const int NFG = *nfg;
  for (int it = 0; it < 16; it++) {
    const int i = it * 512 + blockIdx.x * 4 + w;   // wave-uniform row
    const int lab = labels[i];
    if (lab > 0 && lab < 32) {                     // fg row
      const float iou = ious[i];
      const float iw = (iou > 0.5f) ? iou : 0.f;
      float dot = 0.f, ssq = 0.f;
#pragma unroll
      for (int p = 0; p < 2; p++) {
        const int k = lane + p * 64;
        const float z = bf2f(Zc[(size_t)i * 128 + k]);
        dot = fmaf(z, Scls[lab * 128 + k], dot);
        ssq = fmaf(z, z, ssq);
      }
      float zf = bf2f(Zf[(size_t)i * 64 + lane]);
      float ssqf = zf * zf;
#pragma unroll
      for (int off = 1; off < 64; off <<= 1) {
        dot += __shfl_xor(dot, off, 64);
        ssq += __shfl_xor(ssq, off, 64);
        ssqf += __shfl_xor(ssqf, off, 64);
      }
      if (lane == 0) {
        const float ef = EXP2F(K_LOG2E * ssqf);   // diag term exp(sim_ii/tau), fg head
        if (NFG - 1 > 0) {  // n_pos = NFG - 1 for fg rows
          const float D = rowD[i] - ef;
          const float Nn = rowN[i] - ef;
          const float loss = logf(D + 2e-8f) - logf(Nn + 1e-8f);
          aw0 += iw;
          al0 += iw * loss;
        }
        const int npc = hist[lab];
        if (npc > 0) {
          const float S = rowS[i] - EXP2F(K_LOG2E * ssq);  // remove cls diag
          const float logden = logf(S);
          // sum_log_p = sum_{pos,j!=i}(sim) - (npc-1)*logden + NEG(diag)
          const float slp = (dot - ssq) * 5.0f - (float)(npc - 1) * logden - 1e9f;
          aw1 += iw;
          al1 += iw * (-slp / ((float)npc + 1e-8f));
        }
      }
    }
  }
  if (lane == 0) { red[w][0] = aw0; red[w][1] = al0; red[w][2] = aw1; red[w][3] = al1; }
  __syncthreads();
  if (t < 4) atomicAdd(&scal[t], red[0][t] + red[1][t] + red[2][t] + red[3][t]);
}

__global__ void writeout_kernel(const float* __restrict__ scal, float* __restrict__ out) {
  if (threadIdx.x == 0) {
    out[0] = scal[1] / (scal[0] + 1e-8f);
    out[1] = scal[3] / (scal[2] + 1e-8f);
  }
}

// ---------------- launch ----------------
extern "C" void kernel_launch(void* const* d_in, const int* in_sizes, int n_in,
                              void* d_out, int out_size, void* d_ws, size_t ws_size,
                              hipStream_t stream) {
  (void)in_sizes; (void)n_in; (void)out_size; (void)ws_size;
  const float* roi    = (const float*)d_in[0];
  const int*   labels = (const int*)d_in[1];
  const float* ious   = (const float*)d_in[2];
  const float* fgw1   = (const float*)d_in[3];
  const float* fgb1   = (const float*)d_in[4];
  const float* fgw2   = (const float*)d_in[5];
  const float* fgb2   = (const float*)d_in[6];
  const float* clsw1  = (const float*)d_in[7];
  const float* clsb1  = (const float*)d_in[8];
  const float* clsw2  = (const float*)d_in[9];
  const float* clsb2  = (const float*)d_in[10];

  char* ws = (char*)d_ws;
  unsigned short* W1T  = (unsigned short*)(ws + O_W1T);
  unsigned short* W2Tf = (unsigned short*)(ws + O_W2TF);
  unsigned short* W2Tc = (unsigned short*)(ws + O_W2TC);
  unsigned short* Hb   = (unsigned short*)(ws + O_H);
  unsigned short* Zf   = (unsigned short*)(ws + O_ZF);
  unsigned short* Zc   = (unsigned short*)(ws + O_ZC);
  float* Scls = (float*)(ws + O_SCLS);
  float* rowD = (float*)(ws + O_ROWD);
  float* rowN = (float*)(ws + O_ROWN);
  float* rowS = (float*)(ws + O_ROWS);
  float* scal = (float*)(ws + O_SCAL);
  int* hist = (int*)(ws + O_HIST);
  int* nfg  = (int*)(ws + O_NFG);
  float* out = (float*)d_out;

  hipLaunchKernelGGL(zero_kernel, dim3((ZERO_WORDS + 255) / 256), dim3(256), 0, stream,
                     (float*)(ws + O_SCLS), ZERO_WORDS);
  hipLaunchKernelGGL(transp_kernel, dim3(64, 4), dim3(256), 0, stream,
                     fgw1, clsw1, fgw2, clsw2, W1T, W2Tf, W2Tc);
  hipLaunchKernelGGL(meta_kernel, dim3(32), dim3(256), 0, stream, labels, hist, nfg);
  hipLaunchKernelGGL(gemm1_kernel, dim3(64, 8), dim3(256), 0, stream,
                     roi, W1T, fgb1, clsb1, Hb);
  hipLaunchKernelGGL(gemm2_kernel, dim3(256), dim3(256), 0, stream,
                     Hb, W2Tf, W2Tc, fgb2, clsb2, Zf, Zc);
  hipLaunchKernelGGL(scls_kernel, dim3(20, 32), dim3(128), 0, stream, Zc, labels, Scls);
  hipLaunchKernelGGL(sim_kernel, dim3(64, 16), dim3(256), 0, stream,
                     Zf, Zc, labels, rowD, rowN, rowS);
  hipLaunchKernelGGL(finalize_kernel, dim3(128), dim3(256), 0, stream,
                     Zf, Zc, labels, ious, rowD, rowN, rowS, Scls, hist, nfg, scal);
  hipLaunchKernelGGL(writeout_kernel, dim3(1), dim3(64), 0, stream, scal, out);
}